// Round 22
// baseline (158.752 us; speedup 1.0000x reference)
//
#include <hip/hip_runtime.h>

#define NNODES 50000

typedef _Float16 half8 __attribute__((ext_vector_type(8)));
typedef float f32x4 __attribute__((ext_vector_type(4)));

// Fast transcendentals: v_exp_f32 + v_rcp_f32 (validated r20/r21).
__device__ __forceinline__ float sigm(float x) {
    return __builtin_amdgcn_rcpf(1.f + __expf(-x));
}
__device__ __forceinline__ float tanh_f(float x) {
    float e = __expf(2.f * x);
    return 1.f - 2.f * __builtin_amdgcn_rcpf(e + 1.f);
}
__device__ __forceinline__ void sched_fence() { asm volatile("" ::: "memory"); }

// ---------------------------------------------------------------------------
// Merged weight prep (one launch, 704 blocks). Proven r13/r14.
__global__ __launch_bounds__(256) void k_prep(const float* __restrict__ Wc,
                                              const float* __restrict__ Wl,
                                              const float* __restrict__ ce,
                                              const float* __restrict__ Wx,
                                              const float* __restrict__ bx,
                                              const float* __restrict__ bc,
                                              _Float16* __restrict__ WpT,
                                              _Float16* __restrict__ WlT) {
    int b = blockIdx.x;
    if (b < 512) {
        int i = b * 256 + threadIdx.x;           // 0..131071
        int c = i >> 8, k = i & 255;
        int g = c >> 7, d = c & 127;
        float v = (k < 128) ? Wc[(2 * g) * 16384 + k * 128 + d]
                            : Wc[(2 * g + 1) * 16384 + (k - 128) * 128 + d];
        WpT[c * 288 + k] = (_Float16)v;
    } else if (b < 640) {
        int i = (b - 512) * 256 + threadIdx.x;   // 0..32767
        int c = i >> 7, k = i & 127;
        WlT[i] = (_Float16)Wl[(c >> 7) * 16384 + k * 128 + (c & 127)];
    } else {
        int i = (b - 640) * 256 + threadIdx.x;   // 0..16383
        int tt = i >> 9, c = i & 511;
        int g = c >> 7, d = c & 127;
        int gx = (g == 0) ? 0 : ((g == 3) ? 2 : 1);
        float acc = bx[gx * 128 + d] + bc[(2 * g) * 128 + d] + bc[(2 * g + 1) * 128 + d];
        const float* x = ce + tt * 128;
        const float* w = Wx + gx * 16384 + d;
        for (int l = 0; l < 128; ++l) acc += x[l] * w[l * 128];
        WpT[c * 288 + 256 + tt] = (_Float16)acc;
    }
}

// ---------------------------------------------------------------------------
// Leaf tables: [50000 x 128] fp32 -> c_tab fp16, h_tab fp16 via f16 MFMA
__global__ __launch_bounds__(256) void k_prep_nodes(const float* __restrict__ ne,
                                                    const _Float16* __restrict__ WlT,
                                                    const float* __restrict__ bl,
                                                    _Float16* __restrict__ c_tab,
                                                    _Float16* __restrict__ h_tab) {
    const int t = threadIdx.x;
    const int w = t >> 6, l = t & 63;
    const int lr = l & 15, lq = l >> 4;
    const int nb = blockIdx.x * 32;

    int arow[2];
#pragma unroll
    for (int rt = 0; rt < 2; ++rt) {
        int r = nb + rt * 16 + lr;
        arow[rt] = (r < NNODES) ? r : (NNODES - 1);
    }

    f32x4 acc[2][2][2];
#pragma unroll
    for (int rt = 0; rt < 2; ++rt)
#pragma unroll
        for (int g = 0; g < 2; ++g)
#pragma unroll
            for (int ti = 0; ti < 2; ++ti) acc[rt][g][ti] = (f32x4)0.f;

#pragma unroll
    for (int kk = 0; kk < 4; ++kk) {
        half8 af[2];
#pragma unroll
        for (int rt = 0; rt < 2; ++rt) {
            const float* src = ne + (size_t)arow[rt] * 128 + kk * 32 + lq * 8;
            float4 f0 = *(const float4*)src;
            float4 f1 = *(const float4*)(src + 4);
            half8 v;
            v[0] = (_Float16)f0.x; v[1] = (_Float16)f0.y; v[2] = (_Float16)f0.z; v[3] = (_Float16)f0.w;
            v[4] = (_Float16)f1.x; v[5] = (_Float16)f1.y; v[6] = (_Float16)f1.z; v[7] = (_Float16)f1.w;
            af[rt] = v;
        }
#pragma unroll
        for (int g = 0; g < 2; ++g)
#pragma unroll
            for (int ti = 0; ti < 2; ++ti) {
                int col = g * 128 + w * 32 + ti * 16 + lr;
                half8 bb = *(const half8*)(WlT + col * 128 + kk * 32 + lq * 8);
#pragma unroll
                for (int rt = 0; rt < 2; ++rt)
                    acc[rt][g][ti] = __builtin_amdgcn_mfma_f32_16x16x32_f16(af[rt], bb, acc[rt][g][ti], 0, 0, 0);
            }
    }

#pragma unroll
    for (int rt = 0; rt < 2; ++rt)
#pragma unroll
        for (int j = 0; j < 4; ++j) {
            int r = nb + rt * 16 + lq * 4 + j;
            if (r < NNODES) {
#pragma unroll
                for (int ti = 0; ti < 2; ++ti) {
                    int d = w * 32 + ti * 16 + lr;
                    float cc = acc[rt][0][ti][j] + bl[d];
                    float hp = acc[rt][1][ti][j] + bl[128 + d];
                    c_tab[(size_t)r * 128 + d] = (_Float16)cc;
                    h_tab[(size_t)r * 128 + d] = (_Float16)(sigm(hp) * tanh_f(cc));
                }
            }
        }
}

// ---------------------------------------------------------------------------
// k_lo: levels 0-4 fused, 512 blocks x 512 threads (128 L0 pairs/block).
// B[8][4] in 128 regs; kk=8 (tab) B-slice in LDS (s_wp8, stride 32 with XOR
// swizzle r22: elem kt of col c stored at kt ^ ((c&3)<<3); read offset is a
// per-thread constant xoff = (lq ^ (lr&3))*8 -> 8-way bank conflict becomes
// free 2-way, zero register cost). Fences (r18), fast-rcp (r20).
// All passes hand-written (no LICM spill, r5-r8).

struct LoQ { half8 af[8]; _Float16 lcv[4], rcv[4]; };

__device__ __forceinline__ void lo_gather(int qb,
                                          const _Float16* __restrict__ c_tab,
                                          const _Float16* __restrict__ h_tab,
                                          const int* s_leaf,
                                          int lq, int lr, int dcol, LoQ& s) {
#pragma unroll
    for (int j = 0; j < 4; ++j) {
        int p = qb + lq * 4 + j;
        s.lcv[j] = c_tab[(size_t)s_leaf[2 * p] * 128 + dcol];
        s.rcv[j] = c_tab[(size_t)s_leaf[2 * p + 1] * 128 + dcol];
    }
    const int pg = qb + lr;
    const int gl = s_leaf[2 * pg], gr = s_leaf[2 * pg + 1];
#pragma unroll
    for (int kk = 0; kk < 8; ++kk) {
        int row = (kk < 4) ? gl : gr;
        s.af[kk] = *(const half8*)(h_tab + (size_t)row * 128 + (kk & 3) * 32 + lq * 8);
    }
}

__device__ __forceinline__ void lo_mfma(const LoQ& s, int qb,
                                        const _Float16* s_oh, const _Float16* s_wp8,
                                        const half8 (&B)[8][4], int lq, int lr,
                                        int dcol, int xoff,
                                        f32x4 (&acc)[4]) {
#pragma unroll
    for (int g = 0; g < 4; ++g) acc[g] = (f32x4)0.f;
#pragma unroll
    for (int kk = 0; kk < 8; ++kk) {
#pragma unroll
        for (int g = 0; g < 4; ++g)
            acc[g] = __builtin_amdgcn_mfma_f32_16x16x32_f16(s.af[kk], B[kk][g], acc[g], 0, 0, 0);
    }
    {
        half8 a = *(const half8*)(s_oh + (qb + lr) * 36 + lq * 8);
#pragma unroll
        for (int g = 0; g < 4; ++g) {
            half8 b8 = *(const half8*)(s_wp8 + (g * 128 + dcol) * 32 + xoff);
            acc[g] = __builtin_amdgcn_mfma_f32_16x16x32_f16(a, b8, acc[g], 0, 0, 0);
        }
    }
}

__device__ __forceinline__ void lo_epi(const f32x4 (&acc)[4], const LoQ& s, int qb,
                                       _Float16* hA, _Float16* cA, int lq, int dcol) {
#pragma unroll
    for (int j = 0; j < 4; ++j) {
        int p = qb + lq * 4 + j;
        float cc = sigm(acc[0][j]) * tanh_f(acc[3][j])
                 + sigm(acc[1][j]) * (float)s.lcv[j]
                 + sigm(acc[2][j]) * (float)s.rcv[j];
        cA[p * 132 + dcol] = (_Float16)cc;
        hA[p * 128 + (dcol ^ ((p & 15) << 3))] = (_Float16)tanh_f(cc);
    }
}

// Merged 32-pair pass (NRT=2) with base offset, LDS -> LDS.
__device__ __forceinline__ void lds_pass2(int pass0, int opoff,
                                          const _Float16* hS, const _Float16* cS,
                                          _Float16* hD, _Float16* cD,
                                          const _Float16* s_oh, const _Float16* s_wp8,
                                          const half8 (&B)[8][4],
                                          int lq, int lr, int dcol, int xoff) {
    f32x4 acc[2][4];
#pragma unroll
    for (int rt = 0; rt < 2; ++rt)
#pragma unroll
        for (int g = 0; g < 4; ++g) acc[rt][g] = (f32x4)0.f;

#pragma unroll
    for (int kk = 0; kk < 8; ++kk) {
        half8 a[2];
        int side = kk >> 2, ko = (kk & 3) * 32 + lq * 8;
#pragma unroll
        for (int rt = 0; rt < 2; ++rt) {
            int child = 2 * (pass0 + rt * 16 + lr) + side;
            a[rt] = *(const half8*)(hS + child * 128 + (ko ^ ((child & 15) << 3)));
        }
#pragma unroll
        for (int rt = 0; rt < 2; ++rt)
#pragma unroll
            for (int g = 0; g < 4; ++g)
                acc[rt][g] = __builtin_amdgcn_mfma_f32_16x16x32_f16(a[rt], B[kk][g], acc[rt][g], 0, 0, 0);
    }
    {
        half8 a[2];
        a[0] = *(const half8*)(s_oh + (opoff + pass0 + lr) * 36 + lq * 8);
        a[1] = *(const half8*)(s_oh + (opoff + pass0 + 16 + lr) * 36 + lq * 8);
#pragma unroll
        for (int g = 0; g < 4; ++g) {
            half8 b8 = *(const half8*)(s_wp8 + (g * 128 + dcol) * 32 + xoff);
#pragma unroll
            for (int rt = 0; rt < 2; ++rt)
                acc[rt][g] = __builtin_amdgcn_mfma_f32_16x16x32_f16(a[rt], b8, acc[rt][g], 0, 0, 0);
        }
    }

#pragma unroll
    for (int rt = 0; rt < 2; ++rt)
#pragma unroll
        for (int j = 0; j < 4; ++j) {
            int p = pass0 + rt * 16 + lq * 4 + j;
            float vi = acc[rt][0][j], vl = acc[rt][1][j];
            float vr = acc[rt][2][j], vu = acc[rt][3][j];
            float lc = (float)cS[(2 * p) * 132 + dcol];
            float rc = (float)cS[(2 * p + 1) * 132 + dcol];
            float cc = sigm(vi) * tanh_f(vu) + sigm(vl) * lc + sigm(vr) * rc;
            cD[p * 132 + dcol] = (_Float16)cc;
            hD[p * 128 + (dcol ^ ((p & 15) << 3))] = (_Float16)tanh_f(cc);
        }
}

// Single 16-row pass (NP <= 16); G3OUT -> global.
template <int NP, bool G3OUT>
__device__ __forceinline__ void lds_pass(int opoff,
                                         const _Float16* hS, const _Float16* cS,
                                         _Float16* hD, _Float16* cD,
                                         float* __restrict__ gc, _Float16* __restrict__ gh,
                                         int growbase,
                                         const _Float16* s_oh, const _Float16* s_wp8,
                                         const half8 (&B)[8][4],
                                         int lq, int lr, int dcol, int xoff) {
    const int pidx = (NP >= 16) ? lr : (lr & (NP - 1));
    f32x4 acc[4];
#pragma unroll
    for (int g = 0; g < 4; ++g) acc[g] = (f32x4)0.f;
#pragma unroll
    for (int kk = 0; kk < 8; ++kk) {
        int side = kk >> 2, ko = (kk & 3) * 32 + lq * 8;
        int child = 2 * pidx + side;
        half8 a = *(const half8*)(hS + child * 128 + (ko ^ ((child & 15) << 3)));
#pragma unroll
        for (int g = 0; g < 4; ++g)
            acc[g] = __builtin_amdgcn_mfma_f32_16x16x32_f16(a, B[kk][g], acc[g], 0, 0, 0);
    }
    {
        half8 a = *(const half8*)(s_oh + (opoff + pidx) * 36 + lq * 8);
#pragma unroll
        for (int g = 0; g < 4; ++g) {
            half8 b8 = *(const half8*)(s_wp8 + (g * 128 + dcol) * 32 + xoff);
            acc[g] = __builtin_amdgcn_mfma_f32_16x16x32_f16(a, b8, acc[g], 0, 0, 0);
        }
    }
#pragma unroll
    for (int j = 0; j < 4; ++j) {
        int p = lq * 4 + j;
        if (p < NP) {
            float vi = acc[0][j], vl = acc[1][j], vr = acc[2][j], vu = acc[3][j];
            float lc = (float)cS[(2 * p) * 132 + dcol];
            float rc = (float)cS[(2 * p + 1) * 132 + dcol];
            float cc = sigm(vi) * tanh_f(vu) + sigm(vl) * lc + sigm(vr) * rc;
            if constexpr (G3OUT) {
                gc[(size_t)(growbase + p) * 128 + dcol] = cc;
                gh[(size_t)(growbase + p) * 128 + dcol] = (_Float16)tanh_f(cc);
            } else {
                cD[p * 132 + dcol] = (_Float16)cc;
                hD[p * 128 + (dcol ^ ((p & 15) << 3))] = (_Float16)tanh_f(cc);
            }
        }
    }
}

__global__ __launch_bounds__(512, 1) void k_lo(const _Float16* __restrict__ c_tab,
                                               const _Float16* __restrict__ h_tab,
                                               const int* __restrict__ leaf_idx,
                                               const int* __restrict__ op_idx,
                                               const _Float16* __restrict__ WpT,
                                               float* __restrict__ g4c,
                                               _Float16* __restrict__ g4h) {
    __shared__ int s_leaf[256];
    __shared__ int s_op[248];
    __shared__ _Float16 s_oh[248 * 36];
    __shared__ _Float16 s_wp8[512 * 32];     // kk=8 (tab) B-slice, XOR-swizzled
    __shared__ _Float16 hA[128 * 128], cA[128 * 132];
    __shared__ _Float16 hB[64 * 128],  cB[64 * 132];

    const int t = threadIdx.x;
    const int w = t >> 6, l = t & 63, lr = l & 15, lq = l >> 4;
    const int ks = blockIdx.x >> 3, oct = blockIdx.x & 7;
    const int dcol = w * 16 + lr;
    const int xoff = ((lq ^ (lr & 3))) * 8;   // swizzled per-thread read offset

    if (t < 256) s_leaf[t] = leaf_idx[ks * 2048 + oct * 256 + t];
    else if (t < 384) s_op[t - 256] = op_idx[ks * 2047 + oct * 128 + (t - 256)];          // L0:128
    else if (t < 448) s_op[128 + t - 384] = op_idx[ks * 2047 + 1024 + oct * 64 + (t - 384)]; // L1:64
    else if (t < 480) s_op[192 + t - 448] = op_idx[ks * 2047 + 1536 + oct * 32 + (t - 448)]; // L2:32
    else if (t < 496) s_op[224 + t - 480] = op_idx[ks * 2047 + 1792 + oct * 16 + (t - 480)]; // L3:16
    else if (t < 504) s_op[240 + t - 496] = op_idx[ks * 2047 + 1920 + oct * 8 + (t - 496)];  // L4:8

    // kk=8 slice of WpT -> LDS (XOR-swizzled within each 8-elem group)
    for (int i = t; i < 512 * 32; i += 512) {
        int c = i >> 5, kt = i & 31;
        s_wp8[c * 32 + (kt ^ ((c & 3) << 3))] = WpT[c * 288 + 256 + kt];
    }

    // B (kk=0..7) held in 128 regs across all passes
    half8 B[8][4];
#pragma unroll
    for (int kk = 0; kk < 8; ++kk)
#pragma unroll
        for (int g = 0; g < 4; ++g)
            B[kk][g] = *(const half8*)(WpT + (g * 128 + dcol) * 288 + kk * 32 + lq * 8);

    __syncthreads();
    for (int i = t; i < 248 * 32; i += 512) {
        int p = i >> 5, k = i & 31;
        s_oh[p * 36 + k] = (_Float16)((k == s_op[p]) ? 1.f : 0.f);
    }
    __syncthreads();
    sched_fence();

    // ---- L0: 128 pairs, 8 quarters, 2-deep pipelined gathers + fences ----
    LoQ q0, q1;
    f32x4 acc[4];
    lo_gather(0, c_tab, h_tab, s_leaf, lq, lr, dcol, q0);
    sched_fence();

    lo_mfma(q0,   0, s_oh, s_wp8, B, lq, lr, dcol, xoff, acc);
    lo_gather(16, c_tab, h_tab, s_leaf, lq, lr, dcol, q1);
    lo_epi(acc, q0,   0, hA, cA, lq, dcol);
    sched_fence();

    lo_mfma(q1,  16, s_oh, s_wp8, B, lq, lr, dcol, xoff, acc);
    lo_gather(32, c_tab, h_tab, s_leaf, lq, lr, dcol, q0);
    lo_epi(acc, q1,  16, hA, cA, lq, dcol);
    sched_fence();

    lo_mfma(q0,  32, s_oh, s_wp8, B, lq, lr, dcol, xoff, acc);
    lo_gather(48, c_tab, h_tab, s_leaf, lq, lr, dcol, q1);
    lo_epi(acc, q0,  32, hA, cA, lq, dcol);
    sched_fence();

    lo_mfma(q1,  48, s_oh, s_wp8, B, lq, lr, dcol, xoff, acc);
    lo_gather(64, c_tab, h_tab, s_leaf, lq, lr, dcol, q0);
    lo_epi(acc, q1,  48, hA, cA, lq, dcol);
    sched_fence();

    lo_mfma(q0,  64, s_oh, s_wp8, B, lq, lr, dcol, xoff, acc);
    lo_gather(80, c_tab, h_tab, s_leaf, lq, lr, dcol, q1);
    lo_epi(acc, q0,  64, hA, cA, lq, dcol);
    sched_fence();

    lo_mfma(q1,  80, s_oh, s_wp8, B, lq, lr, dcol, xoff, acc);
    lo_gather(96, c_tab, h_tab, s_leaf, lq, lr, dcol, q0);
    lo_epi(acc, q1,  80, hA, cA, lq, dcol);
    sched_fence();

    lo_mfma(q0,  96, s_oh, s_wp8, B, lq, lr, dcol, xoff, acc);
    lo_gather(112, c_tab, h_tab, s_leaf, lq, lr, dcol, q1);
    lo_epi(acc, q0,  96, hA, cA, lq, dcol);
    sched_fence();

    lo_mfma(q1, 112, s_oh, s_wp8, B, lq, lr, dcol, xoff, acc);
    lo_epi(acc, q1, 112, hA, cA, lq, dcol);
    __syncthreads();

    // ---- L1: 64 pairs, hA -> hB (two merged NRT=2 passes) ----
    lds_pass2( 0, 128, hA, cA, hB, cB, s_oh, s_wp8, B, lq, lr, dcol, xoff);
    sched_fence();
    lds_pass2(32, 128, hA, cA, hB, cB, s_oh, s_wp8, B, lq, lr, dcol, xoff);
    __syncthreads();

    // ---- L2: 32 pairs, hB -> hA rows 0-31 ----
    lds_pass2(0, 192, hB, cB, hA, cA, s_oh, s_wp8, B, lq, lr, dcol, xoff);
    __syncthreads();

    // ---- L3: 16 pairs, hA -> hB rows 0-15 ----
    lds_pass<16, false>(224, hA, cA, hB, cB, nullptr, nullptr, 0, s_oh, s_wp8, B, lq, lr, dcol, xoff);
    __syncthreads();

    // ---- L4: 8 pairs, hB -> global g4 ----
    lds_pass<8, true>(240, hB, cB, nullptr, nullptr, g4c, g4h, blockIdx.x * 8,
                      s_oh, s_wp8, B, lq, lr, dcol, xoff);
}

// ---------------------------------------------------------------------------
// k_tail5: levels 5-10 + AND projection, one block per tree, 512 threads.
template <int NRT, bool GSRC>
__device__ __forceinline__ void tail_pass(int np, int pass0, int opoff,
                                          const _Float16* hS, const _Float16* cS,
                                          const _Float16* __restrict__ gh,
                                          const float* __restrict__ gc, int rowbase,
                                          _Float16* hD, _Float16* cD,
                                          const _Float16* s_oh,
                                          const half8 (&B)[9][4],
                                          int w, int lq, int lr) {
    f32x4 acc[NRT][4];
#pragma unroll
    for (int rt = 0; rt < NRT; ++rt)
#pragma unroll
        for (int g = 0; g < 4; ++g) acc[rt][g] = (f32x4)0.f;

    int pidx[NRT];
#pragma unroll
    for (int rt = 0; rt < NRT; ++rt) {
        int p = pass0 + rt * 16 + lr;
        pidx[rt] = (p < np) ? p : (np - 1);
    }

#pragma unroll
    for (int kk = 0; kk < 9; ++kk) {
        half8 a[NRT];
        if (kk < 8) {
            int side = kk >> 2, ko = (kk & 3) * 32 + lq * 8;
#pragma unroll
            for (int rt = 0; rt < NRT; ++rt) {
                int child = 2 * pidx[rt] + side;
                if constexpr (GSRC)
                    a[rt] = *(const half8*)(gh + (size_t)(rowbase + child) * 128 + ko);
                else
                    a[rt] = *(const half8*)(hS + child * 128 + (ko ^ ((child & 15) << 3)));
            }
        } else {
#pragma unroll
            for (int rt = 0; rt < NRT; ++rt)
                a[rt] = *(const half8*)(s_oh + (opoff + pidx[rt]) * 36 + lq * 8);
        }
#pragma unroll
        for (int rt = 0; rt < NRT; ++rt)
#pragma unroll
            for (int g = 0; g < 4; ++g)
                acc[rt][g] = __builtin_amdgcn_mfma_f32_16x16x32_f16(a[rt], B[kk][g], acc[rt][g], 0, 0, 0);
    }

    const int d = w * 16 + lr;
#pragma unroll
    for (int rt = 0; rt < NRT; ++rt)
#pragma unroll
        for (int j = 0; j < 4; ++j) {
            int p = pass0 + rt * 16 + lq * 4 + j;
            if (p < np) {
                float vi = acc[rt][0][j], vl = acc[rt][1][j];
                float vr = acc[rt][2][j], vu = acc[rt][3][j];
                float lc, rc;
                if constexpr (GSRC) {
                    lc = gc[(size_t)(rowbase + 2 * p) * 128 + d];
                    rc = gc[(size_t)(rowbase + 2 * p + 1) * 128 + d];
                } else {
                    lc = (float)cS[(2 * p) * 132 + d];
                    rc = (float)cS[(2 * p + 1) * 132 + d];
                }
                float cc = sigm(vi) * tanh_f(vu) + sigm(vl) * lc + sigm(vr) * rc;
                cD[p * 132 + d] = (_Float16)cc;
                hD[p * 128 + (d ^ ((p & 15) << 3))] = (_Float16)tanh_f(cc);
            }
        }
}

__global__ __launch_bounds__(512, 1) void k_tail5(const float* __restrict__ g4c,
                                                  const _Float16* __restrict__ g4h,
                                                  const int* __restrict__ op_idx,
                                                  const _Float16* __restrict__ WpT,
                                                  const float* __restrict__ Wa,
                                                  const float* __restrict__ ba,
                                                  float* __restrict__ c2,
                                                  float* __restrict__ h2) {
    __shared__ int s_op[64];
    __shared__ _Float16 s_oh[63 * 36];
    __shared__ _Float16 hA[32 * 128], cA[32 * 132];
    __shared__ _Float16 hB[16 * 128], cB[16 * 132];
    const int t = threadIdx.x, w = t >> 6, l = t & 63, lr = l & 15, lq = l >> 4;
    const int tree = blockIdx.x;
    const int rb = tree * 64;

    if (t < 63) s_op[t] = op_idx[tree * 2047 + 1984 + t];
    // s_op offsets: L5:0(32) L6:32(16) L7:48(8) L8:56(4) L9:60(2) L10:62(1)

    half8 B[9][4];
#pragma unroll
    for (int kk = 0; kk < 9; ++kk)
#pragma unroll
        for (int g = 0; g < 4; ++g)
            B[kk][g] = *(const half8*)(WpT + (g * 128 + w * 16 + lr) * 288 + kk * 32 + lq * 8);

    __syncthreads();
    for (int i = t; i < 63 * 32; i += 512) {
        int p = i >> 5, k = i & 31;
        s_oh[p * 36 + k] = (_Float16)((k == s_op[p]) ? 1.f : 0.f);
    }
    __syncthreads();

    // L5: 32 pairs from global g4 -> hA/cA (single NRT=2 pass)
    tail_pass<2, true>(32, 0, 0, nullptr, nullptr, g4h, g4c, rb, hA, cA, s_oh, B, w, lq, lr);
    __syncthreads();
    tail_pass<1, false>(16, 0, 32, hA, cA, nullptr, nullptr, 0, hB, cB, s_oh, B, w, lq, lr);
    __syncthreads();
    tail_pass<1, false>( 8, 0, 48, hB, cB, nullptr, nullptr, 0, hA, cA, s_oh, B, w, lq, lr);
    __syncthreads();
    tail_pass<1, false>( 4, 0, 56, hA, cA, nullptr, nullptr, 0, hB, cB, s_oh, B, w, lq, lr);
    __syncthreads();
    tail_pass<1, false>( 2, 0, 60, hB, cB, nullptr, nullptr, 0, hA, cA, s_oh, B, w, lq, lr);
    __syncthreads();
    tail_pass<1, false>( 1, 0, 62, hA, cA, nullptr, nullptr, 0, hB, cB, s_oh, B, w, lq, lr);
    __syncthreads();

    // AND projection: root = row 0 of B buffers (p=0 swizzle is identity)
    if (t < 256) {
        int dd = t & 127;
        if (t < 128) {
            float a = ba[dd];
            for (int ll = 0; ll < 128; ++ll) a += (float)cB[ll] * Wa[ll * 128 + dd];
            c2[tree * 128 + dd] = a;
        } else {
            float a = ba[128 + dd];
            for (int ll = 0; ll < 128; ++ll) a += (float)hB[ll] * Wa[16384 + ll * 128 + dd];
            h2[tree * 128 + dd] = a;
        }
    }
}

// ---------------------------------------------------------------------------
__global__ __launch_bounds__(128) void k_final(const float* __restrict__ c2,
                                               const float* __restrict__ h2,
                                               const float* __restrict__ init_e,
                                               const float* __restrict__ Wo,
                                               const float* __restrict__ bo,
                                               float* __restrict__ out) {
    __shared__ float s[384];
    const int d = threadIdx.x;
    float cm = c2[d], hm = h2[d];
    for (int k = 1; k < 64; ++k) {
        cm = fminf(cm, c2[k * 128 + d]);
        hm = fminf(hm, h2[k * 128 + d]);
    }
    s[d] = init_e[d];
    s[128 + d] = cm;
    s[256 + d] = hm;
    __syncthreads();
    float a = bo[d];
    for (int l = 0; l < 384; ++l) a += s[l] * Wo[l * 128 + d];
    out[d] = tanhf(a);
}

// ---------------------------------------------------------------------------
extern "C" void kernel_launch(void* const* d_in, const int* in_sizes, int n_in,
                              void* d_out, int out_size, void* d_ws, size_t ws_size,
                              hipStream_t stream) {
    const float* node_emb = (const float*)d_in[0];
    const float* init_emb = (const float*)d_in[1];
    const float* char_emb = (const float*)d_in[2];
    const float* W_child  = (const float*)d_in[3];
    const float* b_child  = (const float*)d_in[4];
    const float* W_x      = (const float*)d_in[5];
    const float* b_x      = (const float*)d_in[6];
    const float* W_leaf   = (const float*)d_in[7];
    const float* b_leaf   = (const float*)d_in[8];
    const float* W_and    = (const float*)d_in[9];
    const float* b_and    = (const float*)d_in[10];
    const float* W_oend   = (const float*)d_in[11];
    const float* b_oend   = (const float*)d_in[12];
    const int* leaf_idx   = (const int*)d_in[13];
    const int* op_idx     = (const int*)d_in[14];
    float* out = (float*)d_out;
    (void)in_sizes; (void)n_in; (void)out_size; (void)ws_size;

    char* p = (char*)d_ws;
    auto carve = [&](size_t bytes) { char* r = p; p += (bytes + 255) & ~255ull; return r; };
    _Float16* WpT   = (_Float16*)carve((size_t)512 * 288 * 2);
    _Float16* WlT   = (_Float16*)carve((size_t)256 * 128 * 2);
    _Float16* c_tab = (_Float16*)carve((size_t)NNODES * 128 * 2);
    _Float16* h_tab = (_Float16*)carve((size_t)NNODES * 128 * 2);
    float*    g4c   = (float*)carve((size_t)4096 * 128 * 4);
    _Float16* g4h   = (_Float16*)carve((size_t)4096 * 128 * 2);
    float*    c2    = (float*)carve(64 * 128 * 4);
    float*    h2    = (float*)carve(64 * 128 * 4);

    k_prep      <<<704, 256, 0, stream>>>(W_child, W_leaf, char_emb, W_x, b_x, b_child, WpT, WlT);
    k_prep_nodes<<<(NNODES + 31) / 32, 256, 0, stream>>>(node_emb, WlT, b_leaf, c_tab, h_tab);

    k_lo   <<<512, 512, 0, stream>>>(c_tab, h_tab, leaf_idx, op_idx, WpT, g4c, g4h);
    k_tail5<<< 64, 512, 0, stream>>>(g4c, g4h, op_idx, WpT, W_and, b_and, c2, h2);
    k_final<<<1, 128, 0, stream>>>(c2, h2, init_emb, W_oend, b_oend, out);
}

// Round 23
// 151.126 us; speedup vs baseline: 1.0505x; 1.0505x over previous
//
#include <hip/hip_runtime.h>

#define NNODES 50000

typedef _Float16 half8 __attribute__((ext_vector_type(8)));
typedef float f32x4 __attribute__((ext_vector_type(4)));

// Fast transcendentals: v_exp_f32 + v_rcp_f32 (validated r20, absmax unchanged).
__device__ __forceinline__ float sigm(float x) {
    return __builtin_amdgcn_rcpf(1.f + __expf(-x));
}
__device__ __forceinline__ float tanh_f(float x) {
    float e = __expf(2.f * x);
    return 1.f - 2.f * __builtin_amdgcn_rcpf(e + 1.f);
}
__device__ __forceinline__ void sched_fence() { asm volatile("" ::: "memory"); }

// ---------------------------------------------------------------------------
// Merged weight prep (one launch, 704 blocks). Proven r13/r14.
__global__ __launch_bounds__(256) void k_prep(const float* __restrict__ Wc,
                                              const float* __restrict__ Wl,
                                              const float* __restrict__ ce,
                                              const float* __restrict__ Wx,
                                              const float* __restrict__ bx,
                                              const float* __restrict__ bc,
                                              _Float16* __restrict__ WpT,
                                              _Float16* __restrict__ WlT) {
    int b = blockIdx.x;
    if (b < 512) {
        int i = b * 256 + threadIdx.x;           // 0..131071
        int c = i >> 8, k = i & 255;
        int g = c >> 7, d = c & 127;
        float v = (k < 128) ? Wc[(2 * g) * 16384 + k * 128 + d]
                            : Wc[(2 * g + 1) * 16384 + (k - 128) * 128 + d];
        WpT[c * 288 + k] = (_Float16)v;
    } else if (b < 640) {
        int i = (b - 512) * 256 + threadIdx.x;   // 0..32767
        int c = i >> 7, k = i & 127;
        WlT[i] = (_Float16)Wl[(c >> 7) * 16384 + k * 128 + (c & 127)];
    } else {
        int i = (b - 640) * 256 + threadIdx.x;   // 0..16383
        int tt = i >> 9, c = i & 511;
        int g = c >> 7, d = c & 127;
        int gx = (g == 0) ? 0 : ((g == 3) ? 2 : 1);
        float acc = bx[gx * 128 + d] + bc[(2 * g) * 128 + d] + bc[(2 * g + 1) * 128 + d];
        const float* x = ce + tt * 128;
        const float* w = Wx + gx * 16384 + d;
        for (int l = 0; l < 128; ++l) acc += x[l] * w[l * 128];
        WpT[c * 288 + 256 + tt] = (_Float16)acc;
    }
}

// ---------------------------------------------------------------------------
// Leaf tables: [50000 x 128] fp32 -> c_tab fp16, h_tab fp16 via f16 MFMA
__global__ __launch_bounds__(256) void k_prep_nodes(const float* __restrict__ ne,
                                                    const _Float16* __restrict__ WlT,
                                                    const float* __restrict__ bl,
                                                    _Float16* __restrict__ c_tab,
                                                    _Float16* __restrict__ h_tab) {
    const int t = threadIdx.x;
    const int w = t >> 6, l = t & 63;
    const int lr = l & 15, lq = l >> 4;
    const int nb = blockIdx.x * 32;

    int arow[2];
#pragma unroll
    for (int rt = 0; rt < 2; ++rt) {
        int r = nb + rt * 16 + lr;
        arow[rt] = (r < NNODES) ? r : (NNODES - 1);
    }

    f32x4 acc[2][2][2];
#pragma unroll
    for (int rt = 0; rt < 2; ++rt)
#pragma unroll
        for (int g = 0; g < 2; ++g)
#pragma unroll
            for (int ti = 0; ti < 2; ++ti) acc[rt][g][ti] = (f32x4)0.f;

#pragma unroll
    for (int kk = 0; kk < 4; ++kk) {
        half8 af[2];
#pragma unroll
        for (int rt = 0; rt < 2; ++rt) {
            const float* src = ne + (size_t)arow[rt] * 128 + kk * 32 + lq * 8;
            float4 f0 = *(const float4*)src;
            float4 f1 = *(const float4*)(src + 4);
            half8 v;
            v[0] = (_Float16)f0.x; v[1] = (_Float16)f0.y; v[2] = (_Float16)f0.z; v[3] = (_Float16)f0.w;
            v[4] = (_Float16)f1.x; v[5] = (_Float16)f1.y; v[6] = (_Float16)f1.z; v[7] = (_Float16)f1.w;
            af[rt] = v;
        }
#pragma unroll
        for (int g = 0; g < 2; ++g)
#pragma unroll
            for (int ti = 0; ti < 2; ++ti) {
                int col = g * 128 + w * 32 + ti * 16 + lr;
                half8 bb = *(const half8*)(WlT + col * 128 + kk * 32 + lq * 8);
#pragma unroll
                for (int rt = 0; rt < 2; ++rt)
                    acc[rt][g][ti] = __builtin_amdgcn_mfma_f32_16x16x32_f16(af[rt], bb, acc[rt][g][ti], 0, 0, 0);
            }
    }

#pragma unroll
    for (int rt = 0; rt < 2; ++rt)
#pragma unroll
        for (int j = 0; j < 4; ++j) {
            int r = nb + rt * 16 + lq * 4 + j;
            if (r < NNODES) {
#pragma unroll
                for (int ti = 0; ti < 2; ++ti) {
                    int d = w * 32 + ti * 16 + lr;
                    float cc = acc[rt][0][ti][j] + bl[d];
                    float hp = acc[rt][1][ti][j] + bl[128 + d];
                    c_tab[(size_t)r * 128 + d] = (_Float16)cc;
                    h_tab[(size_t)r * 128 + d] = (_Float16)(sigm(hp) * tanh_f(cc));
                }
            }
        }
}

// ---------------------------------------------------------------------------
// k_lo: levels 0-4 fused, 512 blocks x 512 threads (128 L0 pairs/block).
// B[8][4] in 128 regs; kk=8 (tab) B-slice in LDS (s_wp8, stride 32 — the
// r20 stride-36 padding and the r22 XOR swizzle both raised spill via extra
// addressing registers, so the 8-way conflict on 4 ds_reads/pass is the
// cheaper evil); fences (r18); fast-rcp epilogues (r20). All passes
// hand-written (no LICM spill, r5-r8). FROZEN r21 configuration.

struct LoQ { half8 af[8]; _Float16 lcv[4], rcv[4]; };

__device__ __forceinline__ void lo_gather(int qb,
                                          const _Float16* __restrict__ c_tab,
                                          const _Float16* __restrict__ h_tab,
                                          const int* s_leaf,
                                          int lq, int lr, int dcol, LoQ& s) {
#pragma unroll
    for (int j = 0; j < 4; ++j) {
        int p = qb + lq * 4 + j;
        s.lcv[j] = c_tab[(size_t)s_leaf[2 * p] * 128 + dcol];
        s.rcv[j] = c_tab[(size_t)s_leaf[2 * p + 1] * 128 + dcol];
    }
    const int pg = qb + lr;
    const int gl = s_leaf[2 * pg], gr = s_leaf[2 * pg + 1];
#pragma unroll
    for (int kk = 0; kk < 8; ++kk) {
        int row = (kk < 4) ? gl : gr;
        s.af[kk] = *(const half8*)(h_tab + (size_t)row * 128 + (kk & 3) * 32 + lq * 8);
    }
}

__device__ __forceinline__ void lo_mfma(const LoQ& s, int qb,
                                        const _Float16* s_oh, const _Float16* s_wp8,
                                        const half8 (&B)[8][4], int lq, int lr, int dcol,
                                        f32x4 (&acc)[4]) {
#pragma unroll
    for (int g = 0; g < 4; ++g) acc[g] = (f32x4)0.f;
#pragma unroll
    for (int kk = 0; kk < 8; ++kk) {
#pragma unroll
        for (int g = 0; g < 4; ++g)
            acc[g] = __builtin_amdgcn_mfma_f32_16x16x32_f16(s.af[kk], B[kk][g], acc[g], 0, 0, 0);
    }
    {
        half8 a = *(const half8*)(s_oh + (qb + lr) * 36 + lq * 8);
#pragma unroll
        for (int g = 0; g < 4; ++g) {
            half8 b8 = *(const half8*)(s_wp8 + (g * 128 + dcol) * 32 + lq * 8);
            acc[g] = __builtin_amdgcn_mfma_f32_16x16x32_f16(a, b8, acc[g], 0, 0, 0);
        }
    }
}

__device__ __forceinline__ void lo_epi(const f32x4 (&acc)[4], const LoQ& s, int qb,
                                       _Float16* hA, _Float16* cA, int lq, int dcol) {
#pragma unroll
    for (int j = 0; j < 4; ++j) {
        int p = qb + lq * 4 + j;
        float cc = sigm(acc[0][j]) * tanh_f(acc[3][j])
                 + sigm(acc[1][j]) * (float)s.lcv[j]
                 + sigm(acc[2][j]) * (float)s.rcv[j];
        cA[p * 132 + dcol] = (_Float16)cc;
        hA[p * 128 + (dcol ^ ((p & 15) << 3))] = (_Float16)tanh_f(cc);
    }
}

// Merged 32-pair pass (NRT=2) with base offset, LDS -> LDS.
__device__ __forceinline__ void lds_pass2(int pass0, int opoff,
                                          const _Float16* hS, const _Float16* cS,
                                          _Float16* hD, _Float16* cD,
                                          const _Float16* s_oh, const _Float16* s_wp8,
                                          const half8 (&B)[8][4],
                                          int lq, int lr, int dcol) {
    f32x4 acc[2][4];
#pragma unroll
    for (int rt = 0; rt < 2; ++rt)
#pragma unroll
        for (int g = 0; g < 4; ++g) acc[rt][g] = (f32x4)0.f;

#pragma unroll
    for (int kk = 0; kk < 8; ++kk) {
        half8 a[2];
        int side = kk >> 2, ko = (kk & 3) * 32 + lq * 8;
#pragma unroll
        for (int rt = 0; rt < 2; ++rt) {
            int child = 2 * (pass0 + rt * 16 + lr) + side;
            a[rt] = *(const half8*)(hS + child * 128 + (ko ^ ((child & 15) << 3)));
        }
#pragma unroll
        for (int rt = 0; rt < 2; ++rt)
#pragma unroll
            for (int g = 0; g < 4; ++g)
                acc[rt][g] = __builtin_amdgcn_mfma_f32_16x16x32_f16(a[rt], B[kk][g], acc[rt][g], 0, 0, 0);
    }
    {
        half8 a[2];
        a[0] = *(const half8*)(s_oh + (opoff + pass0 + lr) * 36 + lq * 8);
        a[1] = *(const half8*)(s_oh + (opoff + pass0 + 16 + lr) * 36 + lq * 8);
#pragma unroll
        for (int g = 0; g < 4; ++g) {
            half8 b8 = *(const half8*)(s_wp8 + (g * 128 + dcol) * 32 + lq * 8);
#pragma unroll
            for (int rt = 0; rt < 2; ++rt)
                acc[rt][g] = __builtin_amdgcn_mfma_f32_16x16x32_f16(a[rt], b8, acc[rt][g], 0, 0, 0);
        }
    }

#pragma unroll
    for (int rt = 0; rt < 2; ++rt)
#pragma unroll
        for (int j = 0; j < 4; ++j) {
            int p = pass0 + rt * 16 + lq * 4 + j;
            float vi = acc[rt][0][j], vl = acc[rt][1][j];
            float vr = acc[rt][2][j], vu = acc[rt][3][j];
            float lc = (float)cS[(2 * p) * 132 + dcol];
            float rc = (float)cS[(2 * p + 1) * 132 + dcol];
            float cc = sigm(vi) * tanh_f(vu) + sigm(vl) * lc + sigm(vr) * rc;
            cD[p * 132 + dcol] = (_Float16)cc;
            hD[p * 128 + (dcol ^ ((p & 15) << 3))] = (_Float16)tanh_f(cc);
        }
}

// Single 16-row pass (NP <= 16); G3OUT -> global.
template <int NP, bool G3OUT>
__device__ __forceinline__ void lds_pass(int opoff,
                                         const _Float16* hS, const _Float16* cS,
                                         _Float16* hD, _Float16* cD,
                                         float* __restrict__ gc, _Float16* __restrict__ gh,
                                         int growbase,
                                         const _Float16* s_oh, const _Float16* s_wp8,
                                         const half8 (&B)[8][4],
                                         int lq, int lr, int dcol) {
    const int pidx = (NP >= 16) ? lr : (lr & (NP - 1));
    f32x4 acc[4];
#pragma unroll
    for (int g = 0; g < 4; ++g) acc[g] = (f32x4)0.f;
#pragma unroll
    for (int kk = 0; kk < 8; ++kk) {
        int side = kk >> 2, ko = (kk & 3) * 32 + lq * 8;
        int child = 2 * pidx + side;
        half8 a = *(const half8*)(hS + child * 128 + (ko ^ ((child & 15) << 3)));
#pragma unroll
        for (int g = 0; g < 4; ++g)
            acc[g] = __builtin_amdgcn_mfma_f32_16x16x32_f16(a, B[kk][g], acc[g], 0, 0, 0);
    }
    {
        half8 a = *(const half8*)(s_oh + (opoff + pidx) * 36 + lq * 8);
#pragma unroll
        for (int g = 0; g < 4; ++g) {
            half8 b8 = *(const half8*)(s_wp8 + (g * 128 + dcol) * 32 + lq * 8);
            acc[g] = __builtin_amdgcn_mfma_f32_16x16x32_f16(a, b8, acc[g], 0, 0, 0);
        }
    }
#pragma unroll
    for (int j = 0; j < 4; ++j) {
        int p = lq * 4 + j;
        if (p < NP) {
            float vi = acc[0][j], vl = acc[1][j], vr = acc[2][j], vu = acc[3][j];
            float lc = (float)cS[(2 * p) * 132 + dcol];
            float rc = (float)cS[(2 * p + 1) * 132 + dcol];
            float cc = sigm(vi) * tanh_f(vu) + sigm(vl) * lc + sigm(vr) * rc;
            if constexpr (G3OUT) {
                gc[(size_t)(growbase + p) * 128 + dcol] = cc;
                gh[(size_t)(growbase + p) * 128 + dcol] = (_Float16)tanh_f(cc);
            } else {
                cD[p * 132 + dcol] = (_Float16)cc;
                hD[p * 128 + (dcol ^ ((p & 15) << 3))] = (_Float16)tanh_f(cc);
            }
        }
    }
}

__global__ __launch_bounds__(512, 1) void k_lo(const _Float16* __restrict__ c_tab,
                                               const _Float16* __restrict__ h_tab,
                                               const int* __restrict__ leaf_idx,
                                               const int* __restrict__ op_idx,
                                               const _Float16* __restrict__ WpT,
                                               float* __restrict__ g4c,
                                               _Float16* __restrict__ g4h) {
    __shared__ int s_leaf[256];
    __shared__ int s_op[248];
    __shared__ _Float16 s_oh[248 * 36];
    __shared__ _Float16 s_wp8[512 * 32];     // kk=8 (tab) B-slice, 32 KB
    __shared__ _Float16 hA[128 * 128], cA[128 * 132];
    __shared__ _Float16 hB[64 * 128],  cB[64 * 132];

    const int t = threadIdx.x;
    const int w = t >> 6, l = t & 63, lr = l & 15, lq = l >> 4;
    const int ks = blockIdx.x >> 3, oct = blockIdx.x & 7;
    const int dcol = w * 16 + lr;

    if (t < 256) s_leaf[t] = leaf_idx[ks * 2048 + oct * 256 + t];
    else if (t < 384) s_op[t - 256] = op_idx[ks * 2047 + oct * 128 + (t - 256)];          // L0:128
    else if (t < 448) s_op[128 + t - 384] = op_idx[ks * 2047 + 1024 + oct * 64 + (t - 384)]; // L1:64
    else if (t < 480) s_op[192 + t - 448] = op_idx[ks * 2047 + 1536 + oct * 32 + (t - 448)]; // L2:32
    else if (t < 496) s_op[224 + t - 480] = op_idx[ks * 2047 + 1792 + oct * 16 + (t - 480)]; // L3:16
    else if (t < 504) s_op[240 + t - 496] = op_idx[ks * 2047 + 1920 + oct * 8 + (t - 496)];  // L4:8

    // kk=8 slice of WpT -> LDS (coalesced)
    for (int i = t; i < 512 * 32; i += 512) {
        int c = i >> 5, kt = i & 31;
        s_wp8[i] = WpT[c * 288 + 256 + kt];
    }

    // B (kk=0..7) held in 128 regs across all passes
    half8 B[8][4];
#pragma unroll
    for (int kk = 0; kk < 8; ++kk)
#pragma unroll
        for (int g = 0; g < 4; ++g)
            B[kk][g] = *(const half8*)(WpT + (g * 128 + dcol) * 288 + kk * 32 + lq * 8);

    __syncthreads();
    for (int i = t; i < 248 * 32; i += 512) {
        int p = i >> 5, k = i & 31;
        s_oh[p * 36 + k] = (_Float16)((k == s_op[p]) ? 1.f : 0.f);
    }
    __syncthreads();
    sched_fence();

    // ---- L0: 128 pairs, 8 quarters, 2-deep pipelined gathers + fences ----
    LoQ q0, q1;
    f32x4 acc[4];
    lo_gather(0, c_tab, h_tab, s_leaf, lq, lr, dcol, q0);
    sched_fence();

    lo_mfma(q0,   0, s_oh, s_wp8, B, lq, lr, dcol, acc);
    lo_gather(16, c_tab, h_tab, s_leaf, lq, lr, dcol, q1);
    lo_epi(acc, q0,   0, hA, cA, lq, dcol);
    sched_fence();

    lo_mfma(q1,  16, s_oh, s_wp8, B, lq, lr, dcol, acc);
    lo_gather(32, c_tab, h_tab, s_leaf, lq, lr, dcol, q0);
    lo_epi(acc, q1,  16, hA, cA, lq, dcol);
    sched_fence();

    lo_mfma(q0,  32, s_oh, s_wp8, B, lq, lr, dcol, acc);
    lo_gather(48, c_tab, h_tab, s_leaf, lq, lr, dcol, q1);
    lo_epi(acc, q0,  32, hA, cA, lq, dcol);
    sched_fence();

    lo_mfma(q1,  48, s_oh, s_wp8, B, lq, lr, dcol, acc);
    lo_gather(64, c_tab, h_tab, s_leaf, lq, lr, dcol, q0);
    lo_epi(acc, q1,  48, hA, cA, lq, dcol);
    sched_fence();

    lo_mfma(q0,  64, s_oh, s_wp8, B, lq, lr, dcol, acc);
    lo_gather(80, c_tab, h_tab, s_leaf, lq, lr, dcol, q1);
    lo_epi(acc, q0,  64, hA, cA, lq, dcol);
    sched_fence();

    lo_mfma(q1,  80, s_oh, s_wp8, B, lq, lr, dcol, acc);
    lo_gather(96, c_tab, h_tab, s_leaf, lq, lr, dcol, q0);
    lo_epi(acc, q1,  80, hA, cA, lq, dcol);
    sched_fence();

    lo_mfma(q0,  96, s_oh, s_wp8, B, lq, lr, dcol, acc);
    lo_gather(112, c_tab, h_tab, s_leaf, lq, lr, dcol, q1);
    lo_epi(acc, q0,  96, hA, cA, lq, dcol);
    sched_fence();

    lo_mfma(q1, 112, s_oh, s_wp8, B, lq, lr, dcol, acc);
    lo_epi(acc, q1, 112, hA, cA, lq, dcol);
    __syncthreads();

    // ---- L1: 64 pairs, hA -> hB (two merged NRT=2 passes) ----
    lds_pass2( 0, 128, hA, cA, hB, cB, s_oh, s_wp8, B, lq, lr, dcol);
    sched_fence();
    lds_pass2(32, 128, hA, cA, hB, cB, s_oh, s_wp8, B, lq, lr, dcol);
    __syncthreads();

    // ---- L2: 32 pairs, hB -> hA rows 0-31 ----
    lds_pass2(0, 192, hB, cB, hA, cA, s_oh, s_wp8, B, lq, lr, dcol);
    __syncthreads();

    // ---- L3: 16 pairs, hA -> hB rows 0-15 ----
    lds_pass<16, false>(224, hA, cA, hB, cB, nullptr, nullptr, 0, s_oh, s_wp8, B, lq, lr, dcol);
    __syncthreads();

    // ---- L4: 8 pairs, hB -> global g4 ----
    lds_pass<8, true>(240, hB, cB, nullptr, nullptr, g4c, g4h, blockIdx.x * 8,
                      s_oh, s_wp8, B, lq, lr, dcol);
}

// ---------------------------------------------------------------------------
// k_tail5: levels 5-10 + AND projection, one block per tree, 512 threads.
template <int NRT, bool GSRC>
__device__ __forceinline__ void tail_pass(int np, int pass0, int opoff,
                                          const _Float16* hS, const _Float16* cS,
                                          const _Float16* __restrict__ gh,
                                          const float* __restrict__ gc, int rowbase,
                                          _Float16* hD, _Float16* cD,
                                          const _Float16* s_oh,
                                          const half8 (&B)[9][4],
                                          int w, int lq, int lr) {
    f32x4 acc[NRT][4];
#pragma unroll
    for (int rt = 0; rt < NRT; ++rt)
#pragma unroll
        for (int g = 0; g < 4; ++g) acc[rt][g] = (f32x4)0.f;

    int pidx[NRT];
#pragma unroll
    for (int rt = 0; rt < NRT; ++rt) {
        int p = pass0 + rt * 16 + lr;
        pidx[rt] = (p < np) ? p : (np - 1);
    }

#pragma unroll
    for (int kk = 0; kk < 9; ++kk) {
        half8 a[NRT];
        if (kk < 8) {
            int side = kk >> 2, ko = (kk & 3) * 32 + lq * 8;
#pragma unroll
            for (int rt = 0; rt < NRT; ++rt) {
                int child = 2 * pidx[rt] + side;
                if constexpr (GSRC)
                    a[rt] = *(const half8*)(gh + (size_t)(rowbase + child) * 128 + ko);
                else
                    a[rt] = *(const half8*)(hS + child * 128 + (ko ^ ((child & 15) << 3)));
            }
        } else {
#pragma unroll
            for (int rt = 0; rt < NRT; ++rt)
                a[rt] = *(const half8*)(s_oh + (opoff + pidx[rt]) * 36 + lq * 8);
        }
#pragma unroll
        for (int rt = 0; rt < NRT; ++rt)
#pragma unroll
            for (int g = 0; g < 4; ++g)
                acc[rt][g] = __builtin_amdgcn_mfma_f32_16x16x32_f16(a[rt], B[kk][g], acc[rt][g], 0, 0, 0);
    }

    const int d = w * 16 + lr;
#pragma unroll
    for (int rt = 0; rt < NRT; ++rt)
#pragma unroll
        for (int j = 0; j < 4; ++j) {
            int p = pass0 + rt * 16 + lq * 4 + j;
            if (p < np) {
                float vi = acc[rt][0][j], vl = acc[rt][1][j];
                float vr = acc[rt][2][j], vu = acc[rt][3][j];
                float lc, rc;
                if constexpr (GSRC) {
                    lc = gc[(size_t)(rowbase + 2 * p) * 128 + d];
                    rc = gc[(size_t)(rowbase + 2 * p + 1) * 128 + d];
                } else {
                    lc = (float)cS[(2 * p) * 132 + d];
                    rc = (float)cS[(2 * p + 1) * 132 + d];
                }
                float cc = sigm(vi) * tanh_f(vu) + sigm(vl) * lc + sigm(vr) * rc;
                cD[p * 132 + d] = (_Float16)cc;
                hD[p * 128 + (d ^ ((p & 15) << 3))] = (_Float16)tanh_f(cc);
            }
        }
}

__global__ __launch_bounds__(512, 1) void k_tail5(const float* __restrict__ g4c,
                                                  const _Float16* __restrict__ g4h,
                                                  const int* __restrict__ op_idx,
                                                  const _Float16* __restrict__ WpT,
                                                  const float* __restrict__ Wa,
                                                  const float* __restrict__ ba,
                                                  float* __restrict__ c2,
                                                  float* __restrict__ h2) {
    __shared__ int s_op[64];
    __shared__ _Float16 s_oh[63 * 36];
    __shared__ _Float16 hA[32 * 128], cA[32 * 132];
    __shared__ _Float16 hB[16 * 128], cB[16 * 132];
    const int t = threadIdx.x, w = t >> 6, l = t & 63, lr = l & 15, lq = l >> 4;
    const int tree = blockIdx.x;
    const int rb = tree * 64;

    if (t < 63) s_op[t] = op_idx[tree * 2047 + 1984 + t];
    // s_op offsets: L5:0(32) L6:32(16) L7:48(8) L8:56(4) L9:60(2) L10:62(1)

    half8 B[9][4];
#pragma unroll
    for (int kk = 0; kk < 9; ++kk)
#pragma unroll
        for (int g = 0; g < 4; ++g)
            B[kk][g] = *(const half8*)(WpT + (g * 128 + w * 16 + lr) * 288 + kk * 32 + lq * 8);

    __syncthreads();
    for (int i = t; i < 63 * 32; i += 512) {
        int p = i >> 5, k = i & 31;
        s_oh[p * 36 + k] = (_Float16)((k == s_op[p]) ? 1.f : 0.f);
    }
    __syncthreads();

    // L5: 32 pairs from global g4 -> hA/cA (single NRT=2 pass)
    tail_pass<2, true>(32, 0, 0, nullptr, nullptr, g4h, g4c, rb, hA, cA, s_oh, B, w, lq, lr);
    __syncthreads();
    tail_pass<1, false>(16, 0, 32, hA, cA, nullptr, nullptr, 0, hB, cB, s_oh, B, w, lq, lr);
    __syncthreads();
    tail_pass<1, false>( 8, 0, 48, hB, cB, nullptr, nullptr, 0, hA, cA, s_oh, B, w, lq, lr);
    __syncthreads();
    tail_pass<1, false>( 4, 0, 56, hA, cA, nullptr, nullptr, 0, hB, cB, s_oh, B, w, lq, lr);
    __syncthreads();
    tail_pass<1, false>( 2, 0, 60, hB, cB, nullptr, nullptr, 0, hA, cA, s_oh, B, w, lq, lr);
    __syncthreads();
    tail_pass<1, false>( 1, 0, 62, hA, cA, nullptr, nullptr, 0, hB, cB, s_oh, B, w, lq, lr);
    __syncthreads();

    // AND projection: root = row 0 of B buffers (p=0 swizzle is identity)
    if (t < 256) {
        int dd = t & 127;
        if (t < 128) {
            float a = ba[dd];
            for (int ll = 0; ll < 128; ++ll) a += (float)cB[ll] * Wa[ll * 128 + dd];
            c2[tree * 128 + dd] = a;
        } else {
            float a = ba[128 + dd];
            for (int ll = 0; ll < 128; ++ll) a += (float)hB[ll] * Wa[16384 + ll * 128 + dd];
            h2[tree * 128 + dd] = a;
        }
    }
}

// ---------------------------------------------------------------------------
__global__ __launch_bounds__(128) void k_final(const float* __restrict__ c2,
                                               const float* __restrict__ h2,
                                               const float* __restrict__ init_e,
                                               const float* __restrict__ Wo,
                                               const float* __restrict__ bo,
                                               float* __restrict__ out) {
    __shared__ float s[384];
    const int d = threadIdx.x;
    float cm = c2[d], hm = h2[d];
    for (int k = 1; k < 64; ++k) {
        cm = fminf(cm, c2[k * 128 + d]);
        hm = fminf(hm, h2[k * 128 + d]);
    }
    s[d] = init_e[d];
    s[128 + d] = cm;
    s[256 + d] = hm;
    __syncthreads();
    float a = bo[d];
    for (int l = 0; l < 384; ++l) a += s[l] * Wo[l * 128 + d];
    out[d] = tanhf(a);
}

// ---------------------------------------------------------------------------
extern "C" void kernel_launch(void* const* d_in, const int* in_sizes, int n_in,
                              void* d_out, int out_size, void* d_ws, size_t ws_size,
                              hipStream_t stream) {
    const float* node_emb = (const float*)d_in[0];
    const float* init_emb = (const float*)d_in[1];
    const float* char_emb = (const float*)d_in[2];
    const float* W_child  = (const float*)d_in[3];
    const float* b_child  = (const float*)d_in[4];
    const float* W_x      = (const float*)d_in[5];
    const float* b_x      = (const float*)d_in[6];
    const float* W_leaf   = (const float*)d_in[7];
    const float* b_leaf   = (const float*)d_in[8];
    const float* W_and    = (const float*)d_in[9];
    const float* b_and    = (const float*)d_in[10];
    const float* W_oend   = (const float*)d_in[11];
    const float* b_oend   = (const float*)d_in[12];
    const int* leaf_idx   = (const int*)d_in[13];
    const int* op_idx     = (const int*)d_in[14];
    float* out = (float*)d_out;
    (void)in_sizes; (void)n_in; (void)out_size; (void)ws_size;

    char* p = (char*)d_ws;
    auto carve = [&](size_t bytes) { char* r = p; p += (bytes + 255) & ~255ull; return r; };
    _Float16* WpT   = (_Float16*)carve((size_t)512 * 288 * 2);
    _Float16* WlT   = (_Float16*)carve((size_t)256 * 128 * 2);
    _Float16* c_tab = (_Float16*)carve((size_t)NNODES * 128 * 2);
    _Float16* h_tab = (_Float16*)carve((size_t)NNODES * 128 * 2);
    float*    g4c   = (float*)carve((size_t)4096 * 128 * 4);
    _Float16* g4h   = (_Float16*)carve((size_t)4096 * 128 * 2);
    float*    c2    = (float*)carve(64 * 128 * 4);
    float*    h2    = (float*)carve(64 * 128 * 4);

    k_prep      <<<704, 256, 0, stream>>>(W_child, W_leaf, char_emb, W_x, b_x, b_child, WpT, WlT);
    k_prep_nodes<<<(NNODES + 31) / 32, 256, 0, stream>>>(node_emb, WlT, b_leaf, c_tab, h_tab);

    k_lo   <<<512, 512, 0, stream>>>(c_tab, h_tab, leaf_idx, op_idx, WpT, g4c, g4h);
    k_tail5<<< 64, 512, 0, stream>>>(g4c, g4h, op_idx, WpT, W_and, b_and, c2, h2);
    k_final<<<1, 128, 0, stream>>>(c2, h2, init_emb, W_oend, b_oend, out);
}